// Round 1
// baseline (145.030 us; speedup 1.0000x reference)
//
#include <hip/hip_runtime.h>

#define EPS 1e-5f

__global__ __launch_bounds__(256) void fused_cnn(
    const int* __restrict__ x_img, const int* __restrict__ y_int,
    const float* __restrict__ bias1,
    const float* __restrict__ g1, const float* __restrict__ b1,
    const float* __restrict__ m1, const float* __restrict__ v1,
    const float* __restrict__ g2, const float* __restrict__ b2,
    const float* __restrict__ m2, const float* __restrict__ v2,
    const float* __restrict__ g3, const float* __restrict__ b3,
    const float* __restrict__ m3, const float* __restrict__ v3,
    const float* __restrict__ w2, const float* __restrict__ bias2,
    const float* __restrict__ w3, const float* __restrict__ bias3,
    const float* __restrict__ wfc1, const float* __restrict__ bfc1,
    const float* __restrict__ wfc2, const float* __restrict__ bfc2,
    float* __restrict__ out)
{
    const int b   = blockIdx.x;
    const int tid = threadIdx.x;

    __shared__ __align__(16) float s_img[30*30];      // padded 28x28 image
    __shared__ __align__(16) float s_f1[16*16*16];    // 16ch, padded 14x14 -> 16x16
    __shared__ __align__(16) float s_f2[32*9*9];      // 32ch, padded 7x7 -> 9x9
    __shared__ __align__(16) float s_flat[576];       // 64*3*3
    __shared__ __align__(16) float s_h[128];
    __shared__ float s_y[16*9];
    __shared__ float s_a1[16], s_c1[16];
    __shared__ float s_a2[32], s_c2[32];
    __shared__ float s_a3[64], s_c3[64];

    // ---------------- load + fold BN constants ----------------
    const int* ximg = x_img + b * 784;
    for (int idx = tid; idx < 900; idx += 256) {
        int r = idx / 30, c = idx % 30;
        float v = 0.f;
        if (r >= 1 && r <= 28 && c >= 1 && c <= 28)
            v = (float)ximg[(r - 1) * 28 + (c - 1)];
        s_img[idx] = v;
    }
    for (int idx = tid; idx < 16*256; idx += 256) s_f1[idx] = 0.f;  // zero pad borders
    for (int idx = tid; idx < 32*81;  idx += 256) s_f2[idx] = 0.f;
    if (tid < 144) s_y[tid] = (float)y_int[tid];
    if (tid < 16) {
        float inv = g1[tid] * rsqrtf(v1[tid] + EPS);
        s_a1[tid] = inv * 1e-4f;                               // folds /SCALE
        s_c1[tid] = bias1[tid] * inv + b1[tid] - m1[tid] * inv;
    } else if (tid >= 32 && tid < 64) {
        int c = tid - 32;
        float inv = g2[c] * rsqrtf(v2[c] + EPS);
        s_a2[c] = inv;
        s_c2[c] = bias2[c] * inv + b2[c] - m2[c] * inv;
    } else if (tid >= 64 && tid < 128) {
        int c = tid - 64;
        float inv = g3[c] * rsqrtf(v3[c] + EPS);
        s_a3[c] = inv;
        s_c3[c] = bias3[c] * inv + b3[c] - m3[c] * inv;
    }
    __syncthreads();

    // ---------------- conv1 + BN + ReLU + pool -> s_f1 (padded) ----------------
    for (int idx = tid; idx < 16*196; idx += 256) {
        int c = idx / 196, p = idx % 196;
        int ph = p / 14, pw = p % 14;
        const float* yr = s_y + c * 9;
        float acc00 = 0.f, acc01 = 0.f, acc10 = 0.f, acc11 = 0.f;
        #pragma unroll
        for (int ky = 0; ky < 3; ky++) {
            #pragma unroll
            for (int kx = 0; kx < 3; kx++) {
                float wv = yr[ky*3 + kx];
                int base = (2*ph + ky) * 30 + (2*pw + kx);
                acc00 += s_img[base]      * wv;
                acc01 += s_img[base + 1]  * wv;
                acc10 += s_img[base + 30] * wv;
                acc11 += s_img[base + 31] * wv;
            }
        }
        float a = s_a1[c], cc = s_c1[c];
        float mx = fmaxf(fmaxf(acc00, acc01), fmaxf(acc10, acc11));
        mx = fmaxf(mx * a + cc, 0.f);
        // (a>0 since g1>0, v1>0 -> max commutes with the affine+relu)
        s_f1[c*256 + (ph + 1)*16 + (pw + 1)] = mx;
    }
    __syncthreads();

    // ---------------- conv2 + BN + ReLU + pool -> s_f2 (padded) ----------------
    for (int idx = tid; idx < 32*49; idx += 256) {
        int c = idx / 49, p = idx % 49;
        int ph = p / 7, pw = p % 7;
        float acc00 = 0.f, acc01 = 0.f, acc10 = 0.f, acc11 = 0.f;
        const float* wc = w2 + c * 144;
        for (int ci = 0; ci < 16; ci++) {
            const float* fp = s_f1 + ci * 256;
            const float* wp = wc + ci * 9;
            #pragma unroll
            for (int ky = 0; ky < 3; ky++) {
                #pragma unroll
                for (int kx = 0; kx < 3; kx++) {
                    float wv = wp[ky*3 + kx];
                    int base = (2*ph + ky) * 16 + (2*pw + kx);
                    acc00 += fp[base]      * wv;
                    acc01 += fp[base + 1]  * wv;
                    acc10 += fp[base + 16] * wv;
                    acc11 += fp[base + 17] * wv;
                }
            }
        }
        float a = s_a2[c], cc = s_c2[c];
        float mx = 0.f;
        mx = fmaxf(mx, fmaxf(acc00 * a + cc, 0.f));
        mx = fmaxf(mx, fmaxf(acc01 * a + cc, 0.f));
        mx = fmaxf(mx, fmaxf(acc10 * a + cc, 0.f));
        mx = fmaxf(mx, fmaxf(acc11 * a + cc, 0.f));
        s_f2[c*81 + (ph + 1)*9 + (pw + 1)] = mx;
    }
    __syncthreads();

    // ---------------- conv3 + BN + ReLU + pool -> s_flat ----------------
    for (int idx = tid; idx < 64*9; idx += 256) {
        int c = idx / 9, p = idx % 9;
        int ph = p / 3, pw = p % 3;
        float acc00 = 0.f, acc01 = 0.f, acc10 = 0.f, acc11 = 0.f;
        const float* wc = w3 + c * 288;
        for (int ci = 0; ci < 32; ci++) {
            const float* fp = s_f2 + ci * 81;
            const float* wp = wc + ci * 9;
            #pragma unroll
            for (int ky = 0; ky < 3; ky++) {
                #pragma unroll
                for (int kx = 0; kx < 3; kx++) {
                    float wv = wp[ky*3 + kx];
                    int base = (2*ph + ky) * 9 + (2*pw + kx);
                    acc00 += fp[base]     * wv;
                    acc01 += fp[base + 1] * wv;
                    acc10 += fp[base + 9] * wv;
                    acc11 += fp[base + 10] * wv;
                }
            }
        }
        float a = s_a3[c], cc = s_c3[c];
        float mx = 0.f;
        mx = fmaxf(mx, fmaxf(acc00 * a + cc, 0.f));
        mx = fmaxf(mx, fmaxf(acc01 * a + cc, 0.f));
        mx = fmaxf(mx, fmaxf(acc10 * a + cc, 0.f));
        mx = fmaxf(mx, fmaxf(acc11 * a + cc, 0.f));
        s_flat[c*9 + ph*3 + pw] = mx;
    }
    __syncthreads();

    // ---------------- FC1 (+ReLU): 2 threads per output ----------------
    {
        int o = tid >> 1, half = tid & 1;
        const float4* wrow = (const float4*)(wfc1 + o * 576) + half * 72;
        const float4* fv   = (const float4*)s_flat + half * 72;
        float acc = 0.f;
        #pragma unroll 4
        for (int kk = 0; kk < 72; kk++) {
            float4 w = wrow[kk];
            float4 f = fv[kk];
            acc += w.x*f.x + w.y*f.y + w.z*f.z + w.w*f.w;
        }
        acc += __shfl_xor(acc, 1);
        if (half == 0) s_h[o] = fmaxf(acc + bfc1[o], 0.f);
    }
    __syncthreads();

    // ---------------- FC2: 16 lanes per output, shfl reduce ----------------
    if (tid < 160) {
        int o = tid / 16, l = tid % 16;
        float acc = 0.f;
        #pragma unroll
        for (int k = l; k < 128; k += 16)
            acc += s_h[k] * wfc2[o * 128 + k];
        acc += __shfl_xor(acc, 8);
        acc += __shfl_xor(acc, 4);
        acc += __shfl_xor(acc, 2);
        acc += __shfl_xor(acc, 1);
        if (l == 0) out[b * 10 + o] = acc + bfc2[o];
    }
}

extern "C" void kernel_launch(void* const* d_in, const int* in_sizes, int n_in,
                              void* d_out, int out_size, void* d_ws, size_t ws_size,
                              hipStream_t stream) {
    fused_cnn<<<1024, 256, 0, stream>>>(
        (const int*)d_in[0],   (const int*)d_in[1],   (const float*)d_in[2],
        (const float*)d_in[3], (const float*)d_in[4], (const float*)d_in[5], (const float*)d_in[6],
        (const float*)d_in[7], (const float*)d_in[8], (const float*)d_in[9], (const float*)d_in[10],
        (const float*)d_in[11],(const float*)d_in[12],(const float*)d_in[13],(const float*)d_in[14],
        (const float*)d_in[15],(const float*)d_in[16],
        (const float*)d_in[17],(const float*)d_in[18],
        (const float*)d_in[19],(const float*)d_in[20],
        (const float*)d_in[21],(const float*)d_in[22],
        (float*)d_out);
}

// Round 2
// 81.761 us; speedup vs baseline: 1.7738x; 1.7738x over previous
//
#include <hip/hip_runtime.h>

#define EPS 1e-5f

// ---- ws layout (floats) ----
#define YT_OFF   0        // [9][16]  yt[k][c] = (float)y_int[c][k]
#define W2T_OFF  144      // [16*9][32] w2t[ci*9+k][co]
#define W3T_OFF  4752     // [32*9][64] w3t[ci*9+k][co]
#define A1_OFF   23184
#define C1_OFF   23200
#define A2_OFF   23216
#define C2_OFF   23248
#define A3_OFF   23280
#define C3_OFF   23344
#define WS_FLOATS 23408

__global__ __launch_bounds__(256) void prep_kernel(
    const int* __restrict__ y_int,
    const float* __restrict__ w2, const float* __restrict__ w3,
    const float* __restrict__ bias1,
    const float* __restrict__ g1, const float* __restrict__ b1,
    const float* __restrict__ m1, const float* __restrict__ v1,
    const float* __restrict__ g2, const float* __restrict__ b2,
    const float* __restrict__ m2, const float* __restrict__ v2,
    const float* __restrict__ bias2,
    const float* __restrict__ g3, const float* __restrict__ b3,
    const float* __restrict__ m3, const float* __restrict__ v3,
    const float* __restrict__ bias3,
    float* __restrict__ ws)
{
    int i = blockIdx.x * 256 + threadIdx.x;
    if (i < 144) {
        int k = i >> 4, c = i & 15;
        ws[YT_OFF + i] = (float)y_int[c * 9 + k];
    } else if (i < 4752) {
        int j = i - 144;
        int cik = j >> 5, co = j & 31;
        int ci = cik / 9, k = cik % 9;
        ws[i] = w2[(co * 16 + ci) * 9 + k];
    } else if (i < 23184) {
        int j = i - 4752;
        int cik = j >> 6, co = j & 63;
        int ci = cik / 9, k = cik % 9;
        ws[i] = w3[(co * 32 + ci) * 9 + k];
    } else if (i < WS_FLOATS) {
        int idx = i - 23184;
        if (idx < 16) { int c = idx;
            ws[A1_OFF + c] = g1[c] * rsqrtf(v1[c] + EPS) * 1e-4f;
        } else if (idx < 32) { int c = idx - 16;
            float inv = g1[c] * rsqrtf(v1[c] + EPS);
            ws[C1_OFF + c] = bias1[c] * inv + b1[c] - m1[c] * inv;
        } else if (idx < 64) { int c = idx - 32;
            ws[A2_OFF + c] = g2[c] * rsqrtf(v2[c] + EPS);
        } else if (idx < 96) { int c = idx - 64;
            float inv = g2[c] * rsqrtf(v2[c] + EPS);
            ws[C2_OFF + c] = bias2[c] * inv + b2[c] - m2[c] * inv;
        } else if (idx < 160) { int c = idx - 96;
            ws[A3_OFF + c] = g3[c] * rsqrtf(v3[c] + EPS);
        } else { int c = idx - 160;
            float inv = g3[c] * rsqrtf(v3[c] + EPS);
            ws[C3_OFF + c] = bias3[c] * inv + b3[c] - m3[c] * inv;
        }
    }
}

__global__ __launch_bounds__(256) void fused_cnn(
    const int* __restrict__ x_img,
    const float* __restrict__ ws,
    const float* __restrict__ wfc1, const float* __restrict__ bfc1,
    const float* __restrict__ wfc2, const float* __restrict__ bfc2,
    float* __restrict__ out)
{
    const int b    = blockIdx.x;
    const int tid  = threadIdx.x;
    const int lane = tid & 63;
    const int wv   = __builtin_amdgcn_readfirstlane(tid >> 6);  // wave id 0..3

    __shared__ __align__(16) float smem[900 + 4096 + 2592];  // 30352 B
    float* s_img  = smem;           // [30][30]    phases 0-1
    float* s_f1   = smem + 900;     // 16x[16][16] phases 1-2
    float* s_f2   = smem + 4996;    // 32x[9][9]   phases 2-3
    float* s_pre  = smem + 900;     // [64][36]    phase 3 (aliases s_f1, dead)
    float* s_flat = smem;           // [576]       phase 3b+ (aliases s_img, dead)
    float* s_h    = smem + 576;     // [128]

    // ---------------- phase 0: stage image, zero padded planes ----------------
    const int* ximg = x_img + b * 784;
    for (int i = tid; i < 900; i += 256) {
        int r = i / 30, c = i % 30;
        float v = 0.f;
        if (r >= 1 && r <= 28 && c >= 1 && c <= 28)
            v = (float)ximg[(r - 1) * 28 + (c - 1)];
        s_img[i] = v;
    }
    for (int i = tid; i < 4096; i += 256) s_f1[i] = 0.f;
    for (int i = tid; i < 2592; i += 256) s_f2[i] = 0.f;
    __syncthreads();

    // ---------------- phase 1: conv1 (all 16 ch per thread, SGPR weights) ----
    if (tid < 196) {
        int ph = tid / 14, pw = tid % 14;
        float acc[16][4];
        #pragma unroll
        for (int c = 0; c < 16; c++) {
            acc[c][0] = 0.f; acc[c][1] = 0.f; acc[c][2] = 0.f; acc[c][3] = 0.f;
        }
        const float* imgq = s_img + ph * 60 + pw * 2;
        #pragma unroll
        for (int k = 0; k < 9; k++) {
            const float* ip = imgq + (k / 3) * 30 + (k % 3);
            float x0 = ip[0], x1 = ip[1], x2 = ip[30], x3 = ip[31];
            const float4* yw = (const float4*)(ws + YT_OFF + k * 16);
            float4 wA = yw[0], wB = yw[1], wC = yw[2], wD = yw[3];
            float wr[16] = {wA.x, wA.y, wA.z, wA.w, wB.x, wB.y, wB.z, wB.w,
                            wC.x, wC.y, wC.z, wC.w, wD.x, wD.y, wD.z, wD.w};
            #pragma unroll
            for (int c = 0; c < 16; c++) {
                float w = wr[c];
                acc[c][0] += w * x0; acc[c][1] += w * x1;
                acc[c][2] += w * x2; acc[c][3] += w * x3;
            }
        }
        #pragma unroll
        for (int c = 0; c < 16; c++) {
            float mx = fmaxf(fmaxf(acc[c][0], acc[c][1]), fmaxf(acc[c][2], acc[c][3]));
            float r  = fmaxf(mx * ws[A1_OFF + c] + ws[C1_OFF + c], 0.f);
            s_f1[c * 256 + (ph + 1) * 16 + (pw + 1)] = r;
        }
    }
    __syncthreads();

    // ---------------- phase 2: conv2 (wave=8 ch via s_load, lane=quad) -------
    {
        const bool act = lane < 49;
        const int ph = act ? lane / 7 : 0, pw = act ? lane % 7 : 0;
        float acc[8][4];
        #pragma unroll
        for (int j = 0; j < 8; j++) {
            acc[j][0] = 0.f; acc[j][1] = 0.f; acc[j][2] = 0.f; acc[j][3] = 0.f;
        }
        const float* w2t = ws + W2T_OFF;
        const float* f1q = s_f1 + ph * 32 + pw * 2;
        for (int ci = 0; ci < 16; ci++) {
            const float* fp = f1q + ci * 256;
            #pragma unroll
            for (int k = 0; k < 9; k++) {
                const float* ip = fp + (k / 3) * 16 + (k % 3);
                float x0 = ip[0], x1 = ip[1], x2 = ip[16], x3 = ip[17];
                const float4* wq = (const float4*)(w2t + (ci * 9 + k) * 32 + wv * 8);
                float4 wa = wq[0], wb = wq[1];
                float wr[8] = {wa.x, wa.y, wa.z, wa.w, wb.x, wb.y, wb.z, wb.w};
                #pragma unroll
                for (int j = 0; j < 8; j++) {
                    float w = wr[j];
                    acc[j][0] += w * x0; acc[j][1] += w * x1;
                    acc[j][2] += w * x2; acc[j][3] += w * x3;
                }
            }
        }
        if (act) {
            #pragma unroll
            for (int j = 0; j < 8; j++) {
                int c = wv * 8 + j;
                float mx = fmaxf(fmaxf(acc[j][0], acc[j][1]), fmaxf(acc[j][2], acc[j][3]));
                float r  = fmaxf(mx * ws[A2_OFF + c] + ws[C2_OFF + c], 0.f);
                s_f2[c * 81 + (ph + 1) * 9 + (pw + 1)] = r;
            }
        }
    }
    __syncthreads();

    // ---------------- phase 3: conv3 (wave=16 ch via s_load, lane=position) --
    {
        const bool act = lane < 36;
        const int r = act ? lane / 6 : 0, c = act ? lane % 6 : 0;
        float acc[16];
        #pragma unroll
        for (int j = 0; j < 16; j++) acc[j] = 0.f;
        const float* w3t = ws + W3T_OFF;
        const float* f2q = s_f2 + r * 9 + c;
        for (int ci = 0; ci < 32; ci++) {
            const float* fp = f2q + ci * 81;
            #pragma unroll
            for (int k = 0; k < 9; k++) {
                float x = fp[(k / 3) * 9 + (k % 3)];
                const float4* wq = (const float4*)(w3t + (ci * 9 + k) * 64 + wv * 16);
                float4 w0 = wq[0], w1 = wq[1], w2_ = wq[2], w3_ = wq[3];
                float wr[16] = {w0.x, w0.y, w0.z, w0.w, w1.x, w1.y, w1.z, w1.w,
                                w2_.x, w2_.y, w2_.z, w2_.w, w3_.x, w3_.y, w3_.z, w3_.w};
                #pragma unroll
                for (int j = 0; j < 16; j++) acc[j] += wr[j] * x;
            }
        }
        if (act) {
            #pragma unroll
            for (int j = 0; j < 16; j++)
                s_pre[(wv * 16 + j) * 36 + lane] = acc[j];
        }
    }
    __syncthreads();

    // ---------------- phase 3b: pool3 + affine + relu -> s_flat --------------
    for (int i = tid; i < 576; i += 256) {
        int ch = i / 9, q = i % 9;
        int qr = q / 3, qc = q % 3;
        const float* pp = s_pre + ch * 36 + qr * 12 + qc * 2;
        float mx = fmaxf(fmaxf(pp[0], pp[1]), fmaxf(pp[6], pp[7]));
        float rl = fmaxf(mx * ws[A3_OFF + ch] + ws[C3_OFF + ch], 0.f);
        s_flat[ch * 9 + q] = rl;
    }
    __syncthreads();

    // ---------------- phase 4: FC1 (+ReLU), 2 threads per output -------------
    {
        int o = tid >> 1, half = tid & 1;
        const float4* wrow = (const float4*)(wfc1 + o * 576) + half * 72;
        const float4* fv   = (const float4*)s_flat + half * 72;
        float a = 0.f;
        #pragma unroll 8
        for (int kk = 0; kk < 72; kk++) {
            float4 w = wrow[kk];
            float4 f = fv[kk];
            a += w.x * f.x + w.y * f.y + w.z * f.z + w.w * f.w;
        }
        a += __shfl_xor(a, 1);
        if (half == 0) s_h[o] = fmaxf(a + bfc1[o], 0.f);
    }
    __syncthreads();

    // ---------------- phase 5: FC2 -------------------------------------------
    if (tid < 160) {
        int o = tid / 16, l = tid % 16;
        float a = 0.f;
        #pragma unroll
        for (int k = l; k < 128; k += 16)
            a += s_h[k] * wfc2[o * 128 + k];
        a += __shfl_xor(a, 8);
        a += __shfl_xor(a, 4);
        a += __shfl_xor(a, 2);
        a += __shfl_xor(a, 1);
        if (l == 0) out[b * 10 + o] = a + bfc2[o];
    }
}

extern "C" void kernel_launch(void* const* d_in, const int* in_sizes, int n_in,
                              void* d_out, int out_size, void* d_ws, size_t ws_size,
                              hipStream_t stream) {
    float* ws = (float*)d_ws;
    prep_kernel<<<(WS_FLOATS + 255) / 256, 256, 0, stream>>>(
        (const int*)d_in[1],                       // y_int
        (const float*)d_in[15],                    // w2
        (const float*)d_in[17],                    // w3
        (const float*)d_in[2],                     // bias1
        (const float*)d_in[3], (const float*)d_in[4], (const float*)d_in[5], (const float*)d_in[6],
        (const float*)d_in[7], (const float*)d_in[8], (const float*)d_in[9], (const float*)d_in[10],
        (const float*)d_in[16],                    // bias2
        (const float*)d_in[11], (const float*)d_in[12], (const float*)d_in[13], (const float*)d_in[14],
        (const float*)d_in[18],                    // bias3
        ws);
    fused_cnn<<<1024, 256, 0, stream>>>(
        (const int*)d_in[0],                       // x_img
        ws,
        (const float*)d_in[19], (const float*)d_in[20],  // w_fc1, b_fc1
        (const float*)d_in[21], (const float*)d_in[22],  // w_fc2, b_fc2
        (float*)d_out);
}

// Round 3
// 28.163 us; speedup vs baseline: 5.1496x; 2.9031x over previous
//
#include <hip/hip_runtime.h>
#include <hip/hip_bf16.h>

#define EPS 1e-5f

typedef __attribute__((ext_vector_type(8))) short bf16x8;
typedef __attribute__((ext_vector_type(4))) float f32x4;
#define MFMA16(a, b, c) __builtin_amdgcn_mfma_f32_16x16x32_bf16(a, b, c, 0, 0, 0)

// ---- ws layout ----
// f32  [0..143]    YT[k][c] conv1 weights (k-major, 16ch each)
// f32  [144..367]  consts: a1[16] c1[16] a2[32] c2[32] a3[64] c3[64]
// bf16 half-index 1024  (byte 2048):  W2F  2mt*5ks*64lane*8  = 5120
// bf16 half-index 6144  (byte 12288): W3F  4mt*9ks*64*8      = 18432
// bf16 half-index 24576 (byte 49152): WFC1F 8mt*18ks*64*8    = 73728
#define CST_OFF  144
#define W2F_H    1024
#define W3F_H    6144
#define WFC1F_H  24576
#define PREP_ITEMS (368 + 5120 + 18432 + 73728)

__device__ __forceinline__ unsigned short f2bf(float f) {
    unsigned int u = __builtin_bit_cast(unsigned int, f);
    return (unsigned short)((u + 0x7fffu + ((u >> 16) & 1u)) >> 16);
}

__global__ __launch_bounds__(256) void prep_kernel(
    const int* __restrict__ y_int,
    const float* __restrict__ w2, const float* __restrict__ w3,
    const float* __restrict__ wfc1,
    const float* __restrict__ bias1,
    const float* __restrict__ g1, const float* __restrict__ b1,
    const float* __restrict__ m1, const float* __restrict__ v1,
    const float* __restrict__ g2, const float* __restrict__ b2,
    const float* __restrict__ m2, const float* __restrict__ v2,
    const float* __restrict__ bias2,
    const float* __restrict__ g3, const float* __restrict__ b3,
    const float* __restrict__ m3, const float* __restrict__ v3,
    const float* __restrict__ bias3,
    float* __restrict__ ws)
{
    unsigned short* wsh = (unsigned short*)ws;
    int i = blockIdx.x * 256 + threadIdx.x;
    if (i < 144) {
        int k = i >> 4, c = i & 15;
        ws[i] = (float)y_int[c * 9 + k];
    } else if (i < 368) {
        int idx = i - 144;
        if (idx < 16) { int c = idx;
            ws[CST_OFF + idx] = g1[c] * rsqrtf(v1[c] + EPS) * 1e-4f;
        } else if (idx < 32) { int c = idx - 16;
            float inv = g1[c] * rsqrtf(v1[c] + EPS);
            ws[CST_OFF + idx] = bias1[c] * inv + b1[c] - m1[c] * inv;
        } else if (idx < 64) { int c = idx - 32;
            ws[CST_OFF + idx] = g2[c] * rsqrtf(v2[c] + EPS);
        } else if (idx < 96) { int c = idx - 64;
            float inv = g2[c] * rsqrtf(v2[c] + EPS);
            ws[CST_OFF + idx] = bias2[c] * inv + b2[c] - m2[c] * inv;
        } else if (idx < 160) { int c = idx - 96;
            ws[CST_OFF + idx] = g3[c] * rsqrtf(v3[c] + EPS);
        } else { int c = idx - 160;
            float inv = g3[c] * rsqrtf(v3[c] + EPS);
            ws[CST_OFF + idx] = bias3[c] * inv + b3[c] - m3[c] * inv;
        }
    } else {
        int e = i - 368;
        if (e < 5120) {
            // conv2 A-frags: K ordered as tap-pairs x 16ci; tap 9 = zero pad
            int m = e / 2560, r = e % 2560, s = r >> 9, l = (r >> 3) & 63, j = e & 7;
            int kl  = ((l >> 4) << 3) + j;            // 0..31
            int tap = 2 * s + (kl >> 4), ci = kl & 15;
            int ch  = m * 16 + (l & 15);
            float v = (tap < 9) ? w2[ch * 144 + ci * 9 + tap] : 0.f;
            wsh[W2F_H + e] = f2bf(v);
        } else if (e < 5120 + 18432) {
            int e3 = e - 5120;
            int mt = e3 / 4608, r = e3 % 4608, ks = r >> 9, l = (r >> 3) & 63, j = e3 & 7;
            int ch = mt * 16 + (l & 15), ci = ((l >> 4) << 3) + j;
            wsh[W3F_H + e3] = f2bf(w3[ch * 288 + ci * 9 + ks]);
        } else {
            int ef = e - 23552;
            int mt = ef / 9216, r = ef % 9216, ks = r >> 9, l = (r >> 3) & 63, j = ef & 7;
            int ch = mt * 16 + (l & 15), k = ks * 32 + ((l >> 4) << 3) + j;
            wsh[WFC1F_H + ef] = f2bf(wfc1[ch * 576 + k]);
        }
    }
}

__global__ __launch_bounds__(256) void fused_cnn(
    const int* __restrict__ x_img,
    const float* __restrict__ ws,
    const float* __restrict__ bfc1,
    const float* __restrict__ wfc2, const float* __restrict__ bfc2,
    float* __restrict__ out)
{
    const int b    = blockIdx.x;
    const int tid  = threadIdx.x;
    const int lane = tid & 63;
    const int wv   = __builtin_amdgcn_readfirstlane(tid >> 6);
    const unsigned short* wsh = (const unsigned short*)ws;

    __shared__ __align__(16) float          s_img[900];    // padded 30x30 f32
    __shared__ __align__(16) unsigned short s_f1h[4160];   // [16rows][16cols][16ch] bf16 +guard
    __shared__ __align__(16) unsigned short s_f2h[2592];   // [9][9][32ch] bf16
    __shared__ __align__(16) unsigned short s_flat[576];   // flat, reference order ch*9+pos
    __shared__ __align__(16) float          s_h[128];
    __shared__ __align__(16) float          s_cst[224];

    // ---------------- phase 0: stage ----------------
    const int* ximg = x_img + b * 784;
    for (int i = tid; i < 900; i += 256) {
        int r = i / 30, c = i % 30;
        float v = 0.f;
        if (r >= 1 && r <= 28 && c >= 1 && c <= 28)
            v = (float)ximg[(r - 1) * 28 + (c - 1)];
        s_img[i] = v;
    }
    for (int i = tid; i < 4160; i += 256) s_f1h[i] = 0;
    for (int i = tid; i < 2592; i += 256) s_f2h[i] = 0;
    if (tid < 224) s_cst[tid] = ws[CST_OFF + tid];
    __syncthreads();

    // ---------------- phase 1: conv1 (fp32 VALU, exact) -> s_f1h channels-last
    if (tid < 196) {
        int ph = tid / 14, pw = tid % 14;
        float acc[16][4];
        #pragma unroll
        for (int c = 0; c < 16; c++) {
            acc[c][0] = 0.f; acc[c][1] = 0.f; acc[c][2] = 0.f; acc[c][3] = 0.f;
        }
        const float* imgq = s_img + ph * 60 + pw * 2;
        #pragma unroll
        for (int k = 0; k < 9; k++) {
            const float* ip = imgq + (k / 3) * 30 + (k % 3);
            float x0 = ip[0], x1 = ip[1], x2 = ip[30], x3 = ip[31];
            const float4* yw = (const float4*)(ws + k * 16);
            float4 wA = yw[0], wB = yw[1], wC = yw[2], wD = yw[3];
            float wr[16] = {wA.x, wA.y, wA.z, wA.w, wB.x, wB.y, wB.z, wB.w,
                            wC.x, wC.y, wC.z, wC.w, wD.x, wD.y, wD.z, wD.w};
            #pragma unroll
            for (int c = 0; c < 16; c++) {
                float w = wr[c];
                acc[c][0] += w * x0; acc[c][1] += w * x1;
                acc[c][2] += w * x2; acc[c][3] += w * x3;
            }
        }
        unsigned int pk[8];
        #pragma unroll
        for (int c = 0; c < 16; c += 2) {
            float mx0 = fmaxf(fmaxf(acc[c][0], acc[c][1]), fmaxf(acc[c][2], acc[c][3]));
            float r0  = fmaxf(mx0 * s_cst[c] + s_cst[16 + c], 0.f);
            float mx1 = fmaxf(fmaxf(acc[c+1][0], acc[c+1][1]), fmaxf(acc[c+1][2], acc[c+1][3]));
            float r1  = fmaxf(mx1 * s_cst[c + 1] + s_cst[16 + c + 1], 0.f);
            pk[c >> 1] = (unsigned int)f2bf(r0) | ((unsigned int)f2bf(r1) << 16);
        }
        int pos = (ph + 1) * 16 + (pw + 1);
        *(uint4*)&s_f1h[pos * 16]     = make_uint4(pk[0], pk[1], pk[2], pk[3]);
        *(uint4*)&s_f1h[pos * 16 + 8] = make_uint4(pk[4], pk[5], pk[6], pk[7]);
    }
    __syncthreads();

    // ---------------- phase 2: conv2 via MFMA, pool -> s_f2h ----------------
    {
        const int m = wv & 1;                 // M-tile (16 ch)
        const int x = lane & 15, half = lane >> 4;
        bf16x8 A2[5];
        #pragma unroll
        for (int s = 0; s < 5; s++)
            A2[s] = *(const bf16x8*)(const void*)(wsh + W2F_H + ((m * 5 + s) * 64 + lane) * 8);
        int voff[5];
        #pragma unroll
        for (int s = 0; s < 5; s++) {
            int tap = 2 * s + (half >> 1);
            int dy = (tap < 9) ? tap / 3 : 0, dx = (tap < 9) ? tap % 3 : 0;
            voff[s] = (dy * 16 + x + dx) * 32 + (half & 1) * 16;   // bytes
        }
        const int ch0 = m * 16 + half * 4;
        float a2v[4], c2v[4];
        #pragma unroll
        for (int r = 0; r < 4; r++) { a2v[r] = s_cst[32 + ch0 + r]; c2v[r] = s_cst[64 + ch0 + r]; }

        int p0 = (wv < 2) ? 0 : 4, p1 = (wv < 2) ? 4 : 7;
        for (int p = p0; p < p1; p++) {
            const char* base = (const char*)s_f1h + p * 1024;      // y0 = 2p
            f32x4 acc0 = {0.f, 0.f, 0.f, 0.f}, acc1 = {0.f, 0.f, 0.f, 0.f};
            #pragma unroll
            for (int s = 0; s < 5; s++) {
                bf16x8 b0 = *(const bf16x8*)(const void*)(base + voff[s]);
                bf16x8 b1 = *(const bf16x8*)(const void*)(base + 512 + voff[s]);
                acc0 = MFMA16(A2[s], b0, acc0);
                acc1 = MFMA16(A2[s], b1, acc1);
            }
            float hp[4];
            #pragma unroll
            for (int r = 0; r < 4; r++) {
                float vp = fmaxf(acc0[r], acc1[r]);
                hp[r] = fmaxf(vp, __shfl_xor(vp, 1));
            }
            if (!(x & 1) && x < 14) {
                int xp = x >> 1;
                unsigned int lo = (unsigned int)f2bf(fmaxf(hp[0] * a2v[0] + c2v[0], 0.f)) |
                                  ((unsigned int)f2bf(fmaxf(hp[1] * a2v[1] + c2v[1], 0.f)) << 16);
                unsigned int hi = (unsigned int)f2bf(fmaxf(hp[2] * a2v[2] + c2v[2], 0.f)) |
                                  ((unsigned int)f2bf(fmaxf(hp[3] * a2v[3] + c2v[3], 0.f)) << 16);
                *(uint2*)&s_f2h[((p + 1) * 9 + xp + 1) * 32 + ch0] = make_uint2(lo, hi);
            }
        }
    }
    __syncthreads();

    // ---------------- phase 3: conv3 via MFMA, pool -> s_flat ----------------
    {
        const int mt = wv;                    // M-tile (16 of 64 ch)
        const int x8 = lane & 7, ry = (lane >> 3) & 1, half = lane >> 4;
        bf16x8 A3[9];
        #pragma unroll
        for (int ks = 0; ks < 9; ks++)
            A3[ks] = *(const bf16x8*)(const void*)(wsh + W3F_H + ((mt * 9 + ks) * 64 + lane) * 8);
        int voff3[9];
        #pragma unroll
        for (int ks = 0; ks < 9; ks++) {
            int dy = ks / 3, dx = ks % 3;
            voff3[ks] = ((ry + dy) * 9 + x8 + dx) * 64 + half * 16;  // bytes
        }
        const int ch0 = mt * 16 + half * 4;
        float a3v[4], c3v[4];
        #pragma unroll
        for (int r = 0; r < 4; r++) { a3v[r] = s_cst[96 + ch0 + r]; c3v[r] = s_cst[160 + ch0 + r]; }

        #pragma unroll
        for (int t = 0; t < 3; t++) {
            const char* base = (const char*)s_f2h + t * 1152;   // 2 rows x 9 pos x 64B
            f32x4 acc = {0.f, 0.f, 0.f, 0.f};
            #pragma unroll
            for (int ks = 0; ks < 9; ks++) {
                bf16x8 bb = *(const bf16x8*)(const void*)(base + voff3[ks]);
                acc = MFMA16(A3[ks], bb, acc);
            }
            float hp[4];
            #pragma unroll
            for (int r = 0; r < 4; r++) {
                float vp = fmaxf(acc[r], __shfl_xor(acc[r], 8));
                hp[r] = fmaxf(vp, __shfl_xor(vp, 1));
            }
            if (ry == 0 && !(x8 & 1) && x8 < 6) {
                int xp = x8 >> 1;
                #pragma unroll
                for (int r = 0; r < 4; r++) {
                    float v = fmaxf(hp[r] * a3v[r] + c3v[r], 0.f);
                    s_flat[(ch0 + r) * 9 + t * 3 + xp] = f2bf(v);
                }
            }
        }
    }
    __syncthreads();

    // ---------------- phase 4: FC1 via MFMA (+ReLU) -> s_h -------------------
    {
        #pragma unroll
        for (int mi = 0; mi < 2; mi++) {
            int mt = wv + mi * 4;
            f32x4 acc = {0.f, 0.f, 0.f, 0.f};
            #pragma unroll
            for (int ks = 0; ks < 18; ks++) {
                bf16x8 a  = *(const bf16x8*)(const void*)(wsh + WFC1F_H + ((mt * 18 + ks) * 64 + lane) * 8);
                bf16x8 bb = *(const bf16x8*)(const void*)(&s_flat[ks * 32 + (lane >> 4) * 8]);
                acc = MFMA16(a, bb, acc);
            }
            if ((lane & 15) == 0) {
                int ch0 = mt * 16 + (lane >> 4) * 4;
                #pragma unroll
                for (int r = 0; r < 4; r++)
                    s_h[ch0 + r] = fmaxf(acc[r] + bfc1[ch0 + r], 0.f);
            }
        }
    }
    __syncthreads();

    // ---------------- phase 5: FC2 -------------------------------------------
    if (tid < 160) {
        int o = tid / 16, l = tid % 16;
        float a = 0.f;
        #pragma unroll
        for (int k = l; k < 128; k += 16)
            a += s_h[k] * wfc2[o * 128 + k];
        a += __shfl_xor(a, 8);
        a += __shfl_xor(a, 4);
        a += __shfl_xor(a, 2);
        a += __shfl_xor(a, 1);
        if (l == 0) out[b * 10 + o] = a + bfc2[o];
    }
}

extern "C" void kernel_launch(void* const* d_in, const int* in_sizes, int n_in,
                              void* d_out, int out_size, void* d_ws, size_t ws_size,
                              hipStream_t stream) {
    float* ws = (float*)d_ws;
    prep_kernel<<<(PREP_ITEMS + 255) / 256, 256, 0, stream>>>(
        (const int*)d_in[1],                        // y_int
        (const float*)d_in[15],                     // w2
        (const float*)d_in[17],                     // w3
        (const float*)d_in[19],                     // w_fc1
        (const float*)d_in[2],                      // bias1
        (const float*)d_in[3], (const float*)d_in[4], (const float*)d_in[5], (const float*)d_in[6],
        (const float*)d_in[7], (const float*)d_in[8], (const float*)d_in[9], (const float*)d_in[10],
        (const float*)d_in[16],                     // bias2
        (const float*)d_in[11], (const float*)d_in[12], (const float*)d_in[13], (const float*)d_in[14],
        (const float*)d_in[18],                     // bias3
        ws);
    fused_cnn<<<1024, 256, 0, stream>>>(
        (const int*)d_in[0],                        // x_img
        ws,
        (const float*)d_in[20],                     // b_fc1
        (const float*)d_in[21], (const float*)d_in[22],  // w_fc2, b_fc2
        (float*)d_out);
}

// Round 4
// 27.457 us; speedup vs baseline: 5.2821x; 1.0257x over previous
//
#include <hip/hip_runtime.h>
#include <hip/hip_bf16.h>

#define EPS 1e-5f

typedef __attribute__((ext_vector_type(8))) short bf16x8;
typedef __attribute__((ext_vector_type(4))) float f32x4;
#define MFMA16(a, b, c) __builtin_amdgcn_mfma_f32_16x16x32_bf16(a, b, c, 0, 0, 0)

// ---- ws layout ----
// f32  [0..143]    YT[k][c] conv1 weights (k-major, 16ch each)
// f32  [144..367]  consts: a1[16] c1[16] a2[32] c2[32] a3[64] c3[64]
// bf16 half-index 1024  (byte 2048):  W2F  2mt*5ks*64lane*8  = 5120
// bf16 half-index 6144  (byte 12288): W3F  4mt*9ks*64*8      = 18432
// bf16 half-index 24576 (byte 49152): WFC1F 8mt*18ks*64*8    = 73728
#define CST_OFF  144
#define W2F_H    1024
#define W3F_H    6144
#define WFC1F_H  24576
#define PREP_ITEMS (368 + 5120 + 18432 + 73728)

__device__ __forceinline__ unsigned short f2bf(float f) {
    unsigned int u = __builtin_bit_cast(unsigned int, f);
    return (unsigned short)((u + 0x7fffu + ((u >> 16) & 1u)) >> 16);
}

__global__ __launch_bounds__(256) void prep_kernel(
    const int* __restrict__ y_int,
    const float* __restrict__ w2, const float* __restrict__ w3,
    const float* __restrict__ wfc1,
    const float* __restrict__ bias1,
    const float* __restrict__ g1, const float* __restrict__ b1,
    const float* __restrict__ m1, const float* __restrict__ v1,
    const float* __restrict__ g2, const float* __restrict__ b2,
    const float* __restrict__ m2, const float* __restrict__ v2,
    const float* __restrict__ bias2,
    const float* __restrict__ g3, const float* __restrict__ b3,
    const float* __restrict__ m3, const float* __restrict__ v3,
    const float* __restrict__ bias3,
    float* __restrict__ ws)
{
    unsigned short* wsh = (unsigned short*)ws;
    int i = blockIdx.x * 256 + threadIdx.x;
    if (i < 144) {
        int k = i >> 4, c = i & 15;
        ws[i] = (float)y_int[c * 9 + k];
    } else if (i < 368) {
        int idx = i - 144;
        if (idx < 16) { int c = idx;
            ws[CST_OFF + idx] = g1[c] * rsqrtf(v1[c] + EPS) * 1e-4f;
        } else if (idx < 32) { int c = idx - 16;
            float inv = g1[c] * rsqrtf(v1[c] + EPS);
            ws[CST_OFF + idx] = bias1[c] * inv + b1[c] - m1[c] * inv;
        } else if (idx < 64) { int c = idx - 32;
            ws[CST_OFF + idx] = g2[c] * rsqrtf(v2[c] + EPS);
        } else if (idx < 96) { int c = idx - 64;
            float inv = g2[c] * rsqrtf(v2[c] + EPS);
            ws[CST_OFF + idx] = bias2[c] * inv + b2[c] - m2[c] * inv;
        } else if (idx < 160) { int c = idx - 96;
            ws[CST_OFF + idx] = g3[c] * rsqrtf(v3[c] + EPS);
        } else { int c = idx - 160;
            float inv = g3[c] * rsqrtf(v3[c] + EPS);
            ws[CST_OFF + idx] = bias3[c] * inv + b3[c] - m3[c] * inv;
        }
    } else {
        int e = i - 368;
        if (e < 5120) {
            // conv2 A-frags: K ordered as tap-pairs x 16ci; tap 9 = zero pad
            int m = e / 2560, r = e % 2560, s = r >> 9, l = (r >> 3) & 63, j = e & 7;
            int kl  = ((l >> 4) << 3) + j;            // 0..31
            int tap = 2 * s + (kl >> 4), ci = kl & 15;
            int ch  = m * 16 + (l & 15);
            float v = (tap < 9) ? w2[ch * 144 + ci * 9 + tap] : 0.f;
            wsh[W2F_H + e] = f2bf(v);
        } else if (e < 5120 + 18432) {
            int e3 = e - 5120;
            int mt = e3 / 4608, r = e3 % 4608, ks = r >> 9, l = (r >> 3) & 63, j = e3 & 7;
            int ch = mt * 16 + (l & 15), ci = ((l >> 4) << 3) + j;
            wsh[W3F_H + e3] = f2bf(w3[ch * 288 + ci * 9 + ks]);
        } else {
            int ef = e - 23552;
            int mt = ef / 9216, r = ef % 9216, ks = r >> 9, l = (r >> 3) & 63, j = ef & 7;
            int ch = mt * 16 + (l & 15), k = ks * 32 + ((l >> 4) << 3) + j;
            wsh[WFC1F_H + ef] = f2bf(wfc1[ch * 576 + k]);
        }
    }
}

__global__ __launch_bounds__(512, 4) void fused_cnn(
    const int* __restrict__ x_img,
    const float* __restrict__ ws,
    const float* __restrict__ bfc1,
    const float* __restrict__ wfc2, const float* __restrict__ bfc2,
    float* __restrict__ out)
{
    const int b    = blockIdx.x;          // covers images 2b, 2b+1
    const int tid  = threadIdx.x;
    const int lane = tid & 63;
    const int wv   = __builtin_amdgcn_readfirstlane(tid >> 6);  // 0..7
    const int img  = wv >> 2;             // image group for conv phases
    const int wv4  = wv & 3;
    const unsigned short* wsh = (const unsigned short*)ws;

    __shared__ __align__(16) float          s_img[2][900];
    __shared__ __align__(16) unsigned short s_f1h[2][4160];  // [16r][16c][16ch] + guard
    __shared__ __align__(16) unsigned short s_f2h[2][2592];  // [9][9][32ch]
    __shared__ __align__(16) unsigned short s_flat[2][576];
    __shared__ __align__(16) float          s_h[2][128];
    __shared__ __align__(16) float          s_cst[224];

    // ---------------- phase 0: stage 2 images, vectorized zero-fill ----------
    const int* ximg = x_img + (b * 2) * 784;
    for (int i = tid; i < 1800; i += 512) {
        int im = i / 900, p = i - im * 900;
        int r = p / 30, c = p % 30;
        float v = 0.f;
        if (r >= 1 && r <= 28 && c >= 1 && c <= 28)
            v = (float)ximg[im * 784 + (r - 1) * 28 + (c - 1)];
        s_img[im][p] = v;
    }
    {
        uint4 z = make_uint4(0u, 0u, 0u, 0u);
        uint4* z1 = (uint4*)&s_f1h[0][0];
        for (int i = tid; i < 1040; i += 512) z1[i] = z;
        uint4* z2 = (uint4*)&s_f2h[0][0];
        for (int i = tid; i < 648; i += 512) z2[i] = z;
    }
    if (tid < 224) s_cst[tid] = ws[CST_OFF + tid];
    __syncthreads();

    // ---------------- phase 1: conv1 (fp32 VALU, exact) -> s_f1h -------------
    {
        const int t  = tid & 255;
        const int ig = tid >> 8;          // 0: waves 0-3, 1: waves 4-7
        if (t < 196) {
            int ph = t / 14, pw = t % 14;
            float acc[16][4];
            #pragma unroll
            for (int c = 0; c < 16; c++) {
                acc[c][0] = 0.f; acc[c][1] = 0.f; acc[c][2] = 0.f; acc[c][3] = 0.f;
            }
            const float* imgq = &s_img[ig][0] + ph * 60 + pw * 2;
            #pragma unroll
            for (int k = 0; k < 9; k++) {
                const float* ip = imgq + (k / 3) * 30 + (k % 3);
                float x0 = ip[0], x1 = ip[1], x2 = ip[30], x3 = ip[31];
                const float4* yw = (const float4*)(ws + k * 16);
                float4 wA = yw[0], wB = yw[1], wC = yw[2], wD = yw[3];
                float wr[16] = {wA.x, wA.y, wA.z, wA.w, wB.x, wB.y, wB.z, wB.w,
                                wC.x, wC.y, wC.z, wC.w, wD.x, wD.y, wD.z, wD.w};
                #pragma unroll
                for (int c = 0; c < 16; c++) {
                    float w = wr[c];
                    acc[c][0] += w * x0; acc[c][1] += w * x1;
                    acc[c][2] += w * x2; acc[c][3] += w * x3;
                }
            }
            unsigned int pk[8];
            #pragma unroll
            for (int c = 0; c < 16; c += 2) {
                float mx0 = fmaxf(fmaxf(acc[c][0], acc[c][1]), fmaxf(acc[c][2], acc[c][3]));
                float r0  = fmaxf(mx0 * s_cst[c] + s_cst[16 + c], 0.f);
                float mx1 = fmaxf(fmaxf(acc[c+1][0], acc[c+1][1]), fmaxf(acc[c+1][2], acc[c+1][3]));
                float r1  = fmaxf(mx1 * s_cst[c + 1] + s_cst[16 + c + 1], 0.f);
                pk[c >> 1] = (unsigned int)f2bf(r0) | ((unsigned int)f2bf(r1) << 16);
            }
            int pos = (ph + 1) * 16 + (pw + 1);
            *(uint4*)&s_f1h[ig][pos * 16]     = make_uint4(pk[0], pk[1], pk[2], pk[3]);
            *(uint4*)&s_f1h[ig][pos * 16 + 8] = make_uint4(pk[4], pk[5], pk[6], pk[7]);
        }
    }
    __syncthreads();

    // ---------------- phase 2: conv2 via MFMA, pool -> s_f2h ----------------
    {
        const int m = wv4 & 1;                // M-tile (16 ch)
        const int x = lane & 15, half = lane >> 4;
        bf16x8 A2[5];
        #pragma unroll
        for (int s = 0; s < 5; s++)
            A2[s] = *(const bf16x8*)(const void*)(wsh + W2F_H + ((m * 5 + s) * 64 + lane) * 8);
        int voff[5];
        #pragma unroll
        for (int s = 0; s < 5; s++) {
            int tap = 2 * s + (half >> 1);
            int dy = (tap < 9) ? tap / 3 : 0, dx = (tap < 9) ? tap % 3 : 0;
            voff[s] = (dy * 16 + x + dx) * 32 + (half & 1) * 16;   // bytes
        }
        const int ch0 = m * 16 + half * 4;
        float a2v[4], c2v[4];
        #pragma unroll
        for (int r = 0; r < 4; r++) { a2v[r] = s_cst[32 + ch0 + r]; c2v[r] = s_cst[64 + ch0 + r]; }

        int p0 = (wv4 < 2) ? 0 : 4, p1 = (wv4 < 2) ? 4 : 7;
        for (int p = p0; p < p1; p++) {
            const char* base = (const char*)&s_f1h[img][0] + p * 1024;  // y0 = 2p
            f32x4 acc0 = {0.f, 0.f, 0.f, 0.f}, acc1 = {0.f, 0.f, 0.f, 0.f};
            #pragma unroll
            for (int s = 0; s < 5; s++) {
                bf16x8 b0 = *(const bf16x8*)(const void*)(base + voff[s]);
                bf16x8 b1 = *(const bf16x8*)(const void*)(base + 512 + voff[s]);
                acc0 = MFMA16(A2[s], b0, acc0);
                acc1 = MFMA16(A2[s], b1, acc1);
            }
            float hp[4];
            #pragma unroll
            for (int r = 0; r < 4; r++) {
                float vp = fmaxf(acc0[r], acc1[r]);
                hp[r] = fmaxf(vp, __shfl_xor(vp, 1));
            }
            if (!(x & 1) && x < 14) {
                int xp = x >> 1;
                unsigned int lo = (unsigned int)f2bf(fmaxf(hp[0] * a2v[0] + c2v[0], 0.f)) |
                                  ((unsigned int)f2bf(fmaxf(hp[1] * a2v[1] + c2v[1], 0.f)) << 16);
                unsigned int hi = (unsigned int)f2bf(fmaxf(hp[2] * a2v[2] + c2v[2], 0.f)) |
                                  ((unsigned int)f2bf(fmaxf(hp[3] * a2v[3] + c2v[3], 0.f)) << 16);
                *(uint2*)&s_f2h[img][((p + 1) * 9 + xp + 1) * 32 + ch0] = make_uint2(lo, hi);
            }
        }
    }
    __syncthreads();

    // ---------------- phase 3: conv3 via MFMA, pool -> s_flat ----------------
    {
        const int mt = wv4;                   // M-tile (16 of 64 ch)
        const int x8 = lane & 7, ry = (lane >> 3) & 1, half = lane >> 4;
        bf16x8 A3[9];
        #pragma unroll
        for (int ks = 0; ks < 9; ks++)
            A3[ks] = *(const bf16x8*)(const void*)(wsh + W3F_H + ((mt * 9 + ks) * 64 + lane) * 8);
        int voff3[9];
        #pragma unroll
        for (int ks = 0; ks < 9; ks++) {
            int dy = ks / 3, dx = ks % 3;
            voff3[ks] = ((ry + dy) * 9 + x8 + dx) * 64 + half * 16;  // bytes
        }
        const int ch0 = mt * 16 + half * 4;
        float a3v[4], c3v[4];
        #pragma unroll
        for (int r = 0; r < 4; r++) { a3v[r] = s_cst[96 + ch0 + r]; c3v[r] = s_cst[160 + ch0 + r]; }

        #pragma unroll
        for (int t = 0; t < 3; t++) {
            const char* base = (const char*)&s_f2h[img][0] + t * 1152;  // 2 rows
            f32x4 acc = {0.f, 0.f, 0.f, 0.f};
            #pragma unroll
            for (int ks = 0; ks < 9; ks++) {
                bf16x8 bb = *(const bf16x8*)(const void*)(base + voff3[ks]);
                acc = MFMA16(A3[ks], bb, acc);
            }
            float hp[4];
            #pragma unroll
            for (int r = 0; r < 4; r++) {
                float vp = fmaxf(acc[r], __shfl_xor(acc[r], 8));
                hp[r] = fmaxf(vp, __shfl_xor(vp, 1));
            }
            if (ry == 0 && !(x8 & 1) && x8 < 6) {
                int xp = x8 >> 1;
                #pragma unroll
                for (int r = 0; r < 4; r++) {
                    float v = fmaxf(hp[r] * a3v[r] + c3v[r], 0.f);
                    s_flat[img][(ch0 + r) * 9 + t * 3 + xp] = f2bf(v);
                }
            }
        }
    }
    __syncthreads();

    // ---------------- phase 4: FC1 via MFMA, both images share weights -------
    {
        const int mt  = wv;                   // 0..7, 16 outputs each
        const int ib  = (lane >> 3) & 1;      // column 0-7 -> img0, 8-15 -> img1
        f32x4 acc = {0.f, 0.f, 0.f, 0.f};
        #pragma unroll
        for (int ks = 0; ks < 18; ks++) {
            bf16x8 a  = *(const bf16x8*)(const void*)(wsh + WFC1F_H + ((mt * 18 + ks) * 64 + lane) * 8);
            bf16x8 bb = *(const bf16x8*)(const void*)(&s_flat[ib][ks * 32 + (lane >> 4) * 8]);
            acc = MFMA16(a, bb, acc);
        }
        if ((lane & 7) == 0) {                // cols 0 and 8
            int ch0 = mt * 16 + (lane >> 4) * 4;
            #pragma unroll
            for (int r = 0; r < 4; r++)
                s_h[ib][ch0 + r] = fmaxf(acc[r] + bfc1[ch0 + r], 0.f);
        }
    }
    __syncthreads();

    // ---------------- phase 5: FC2 (both images) -----------------------------
    if (tid < 320) {
        int im = tid / 160, t = tid - im * 160;
        int o = t / 16, l = t & 15;
        float a = 0.f;
        #pragma unroll
        for (int k = l; k < 128; k += 16)
            a += s_h[im][k] * wfc2[o * 128 + k];
        a += __shfl_xor(a, 8);
        a += __shfl_xor(a, 4);
        a += __shfl_xor(a, 2);
        a += __shfl_xor(a, 1);
        if (l == 0) out[(b * 2 + im) * 10 + o] = a + bfc2[o];
    }
}

extern "C" void kernel_launch(void* const* d_in, const int* in_sizes, int n_in,
                              void* d_out, int out_size, void* d_ws, size_t ws_size,
                              hipStream_t stream) {
    float* ws = (float*)d_ws;
    prep_kernel<<<(PREP_ITEMS + 255) / 256, 256, 0, stream>>>(
        (const int*)d_in[1],                        // y_int
        (const float*)d_in[15],                     // w2
        (const float*)d_in[17],                     // w3
        (const float*)d_in[19],                     // w_fc1
        (const float*)d_in[2],                      // bias1
        (const float*)d_in[3], (const float*)d_in[4], (const float*)d_in[5], (const float*)d_in[6],
        (const float*)d_in[7], (const float*)d_in[8], (const float*)d_in[9], (const float*)d_in[10],
        (const float*)d_in[16],                     // bias2
        (const float*)d_in[11], (const float*)d_in[12], (const float*)d_in[13], (const float*)d_in[14],
        (const float*)d_in[18],                     // bias3
        ws);
    fused_cnn<<<512, 512, 0, stream>>>(
        (const int*)d_in[0],                        // x_img
        ws,
        (const float*)d_in[20],                     // b_fc1
        (const float*)d_in[21], (const float*)d_in[22],  // w_fc2, b_fc2
        (float*)d_out);
}

// Round 6
// 27.281 us; speedup vs baseline: 5.3162x; 1.0065x over previous
//
#include <hip/hip_runtime.h>
#include <hip/hip_bf16.h>

#define EPS 1e-5f

typedef __attribute__((ext_vector_type(8))) short bf16x8;
typedef __attribute__((ext_vector_type(4))) float f32x4;
#define MFMA16(a, b, c) __builtin_amdgcn_mfma_f32_16x16x32_bf16(a, b, c, 0, 0, 0)

// ---- ws layout ----
// f32  [0..143]    YT[k][c] conv1 weights (k-major, 16ch each)
// f32  [144..367]  consts: a1[16] c1[16] a2[32] c2[32] a3[64] c3[64]
// bf16 half-index 1024  (byte 2048):  W2F  2mt*5ks*64lane*8  = 5120
// bf16 half-index 6144  (byte 12288): W3F  4mt*9ks*64*8      = 18432
// bf16 half-index 24576 (byte 49152): WFC1F 8mt*18ks*64*8    = 73728
#define CST_OFF  144
#define W2F_H    1024
#define W3F_H    6144
#define WFC1F_H  24576
#define PREP_ITEMS (368 + 5120 + 18432 + 73728)

// LDS position strides (shorts): odd multiples of 8 shorts (16B) to spread banks
#define S1  24   // f1h: 16ch + 8 pad  (48 B/pos)
#define S2  40   // f2h: 32ch + 8 pad  (80 B/pos)

__device__ __forceinline__ unsigned short f2bf(float f) {
    unsigned int u = __builtin_bit_cast(unsigned int, f);
    return (unsigned short)((u + 0x7fffu + ((u >> 16) & 1u)) >> 16);
}

__global__ __launch_bounds__(256) void prep_kernel(
    const int* __restrict__ y_int,
    const float* __restrict__ w2, const float* __restrict__ w3,
    const float* __restrict__ wfc1,
    const float* __restrict__ bias1,
    const float* __restrict__ g1, const float* __restrict__ b1,
    const float* __restrict__ m1, const float* __restrict__ v1,
    const float* __restrict__ g2, const float* __restrict__ b2,
    const float* __restrict__ m2, const float* __restrict__ v2,
    const float* __restrict__ bias2,
    const float* __restrict__ g3, const float* __restrict__ b3,
    const float* __restrict__ m3, const float* __restrict__ v3,
    const float* __restrict__ bias3,
    float* __restrict__ ws)
{
    unsigned short* wsh = (unsigned short*)ws;
    int i = blockIdx.x * 256 + threadIdx.x;
    if (i < 144) {
        int k = i >> 4, c = i & 15;
        ws[i] = (float)y_int[c * 9 + k];
    } else if (i < 368) {
        int idx = i - 144;
        if (idx < 16) { int c = idx;
            ws[CST_OFF + idx] = g1[c] * rsqrtf(v1[c] + EPS) * 1e-4f;
        } else if (idx < 32) { int c = idx - 16;
            float inv = g1[c] * rsqrtf(v1[c] + EPS);
            ws[CST_OFF + idx] = bias1[c] * inv + b1[c] - m1[c] * inv;
        } else if (idx < 64) { int c = idx - 32;
            ws[CST_OFF + idx] = g2[c] * rsqrtf(v2[c] + EPS);
        } else if (idx < 96) { int c = idx - 64;
            float inv = g2[c] * rsqrtf(v2[c] + EPS);
            ws[CST_OFF + idx] = bias2[c] * inv + b2[c] - m2[c] * inv;
        } else if (idx < 160) { int c = idx - 96;
            ws[CST_OFF + idx] = g3[c] * rsqrtf(v3[c] + EPS);
        } else { int c = idx - 160;
            float inv = g3[c] * rsqrtf(v3[c] + EPS);
            ws[CST_OFF + idx] = bias3[c] * inv + b3[c] - m3[c] * inv;
        }
    } else {
        int e = i - 368;
        if (e < 5120) {
            // conv2 A-frags: K ordered as tap-pairs x 16ci; tap 9 = zero pad
            int m = e / 2560, r = e % 2560, s = r >> 9, l = (r >> 3) & 63, j = e & 7;
            int kl  = ((l >> 4) << 3) + j;            // 0..31
            int tap = 2 * s + (kl >> 4), ci = kl & 15;
            int ch  = m * 16 + (l & 15);
            float v = (tap < 9) ? w2[ch * 144 + ci * 9 + tap] : 0.f;
            wsh[W2F_H + e] = f2bf(v);
        } else if (e < 5120 + 18432) {
            int e3 = e - 5120;
            int mt = e3 / 4608, r = e3 % 4608, ks = r >> 9, l = (r >> 3) & 63, j = e3 & 7;
            int ch = mt * 16 + (l & 15), ci = ((l >> 4) << 3) + j;
            wsh[W3F_H + e3] = f2bf(w3[ch * 288 + ci * 9 + ks]);
        } else {
            int ef = e - 23552;
            int mt = ef / 9216, r = ef % 9216, ks = r >> 9, l = (r >> 3) & 63, j = ef & 7;
            int ch = mt * 16 + (l & 15), k = ks * 32 + ((l >> 4) << 3) + j;
            wsh[WFC1F_H + ef] = f2bf(wfc1[ch * 576 + k]);
        }
    }
}

__global__ __launch_bounds__(512, 4) void fused_cnn(
    const int* __restrict__ x_img,
    const float* __restrict__ ws,
    const float* __restrict__ bfc1,
    const float* __restrict__ wfc2, const float* __restrict__ bfc2,
    float* __restrict__ out)
{
    const int b    = blockIdx.x;          // covers images 2b, 2b+1
    const int tid  = threadIdx.x;
    const int lane = tid & 63;
    const int wv   = __builtin_amdgcn_readfirstlane(tid >> 6);  // 0..7
    const int img  = wv >> 2;             // image group for conv phases
    const int wv4  = wv & 3;
    const unsigned short* wsh = (const unsigned short*)ws;

    __shared__ __align__(16) float          s_img[2][900];
    __shared__ __align__(16) unsigned short s_f1h[2][256 * S1];  // [16r][16c][16ch+pad]
    __shared__ __align__(16) unsigned short s_f2h[2][81 * S2];   // [9][9][32ch+pad]
    __shared__ __align__(16) unsigned short s_flat[2][576];
    __shared__ __align__(16) float          s_h[2][128];
    __shared__ __align__(16) float          s_cst[224];

    // ---------------- phase 0: stage 2 images, vectorized zero-fill ----------
    const int* ximg = x_img + (b * 2) * 784;
    for (int i = tid; i < 1800; i += 512) {
        int im = i / 900, p = i - im * 900;
        int r = p / 30, c = p % 30;
        float v = 0.f;
        if (r >= 1 && r <= 28 && c >= 1 && c <= 28)
            v = (float)ximg[im * 784 + (r - 1) * 28 + (c - 1)];
        s_img[im][p] = v;
    }
    {
        uint4 z = make_uint4(0u, 0u, 0u, 0u);
        uint4* z1 = (uint4*)&s_f1h[0][0];
        for (int i = tid; i < 2 * 256 * S1 / 8; i += 512) z1[i] = z;
        uint4* z2 = (uint4*)&s_f2h[0][0];
        for (int i = tid; i < 2 * 81 * S2 / 8; i += 512) z2[i] = z;
    }
    if (tid < 224) s_cst[tid] = ws[CST_OFF + tid];
    __syncthreads();

    // ---------------- phase 1: conv1 (fp32 VALU, exact) -> s_f1h -------------
    {
        const int t  = tid & 255;
        const int ig = tid >> 8;          // 0: waves 0-3, 1: waves 4-7
        if (t < 196) {
            int ph = t / 14, pw = t % 14;
            float acc[16][4];
            #pragma unroll
            for (int c = 0; c < 16; c++) {
                acc[c][0] = 0.f; acc[c][1] = 0.f; acc[c][2] = 0.f; acc[c][3] = 0.f;
            }
            const float* imgq = &s_img[ig][0] + ph * 60 + pw * 2;
            #pragma unroll
            for (int k = 0; k < 9; k++) {
                const float* ip = imgq + (k / 3) * 30 + (k % 3);
                float x0 = ip[0], x1 = ip[1], x2 = ip[30], x3 = ip[31];
                const float4* yw = (const float4*)(ws + k * 16);
                float4 wA = yw[0], wB = yw[1], wC = yw[2], wD = yw[3];
                float wr[16] = {wA.x, wA.y, wA.z, wA.w, wB.x, wB.y, wB.z, wB.w,
                                wC.x, wC.y, wC.z, wC.w, wD.x, wD.y, wD.z, wD.w};
                #pragma unroll
                for (int c = 0; c < 16; c++) {
                    float w = wr[c];
                    acc[c][0] += w * x0; acc[c][1] += w * x1;
                    acc[c][2] += w * x2; acc[c][3] += w * x3;
                }
            }
            unsigned int pk[8];
            #pragma unroll
            for (int c = 0; c < 16; c += 2) {
                float mx0 = fmaxf(fmaxf(acc[c][0], acc[c][1]), fmaxf(acc[c][2], acc[c][3]));
                float r0  = fmaxf(mx0 * s_cst[c] + s_cst[16 + c], 0.f);
                float mx1 = fmaxf(fmaxf(acc[c+1][0], acc[c+1][1]), fmaxf(acc[c+1][2], acc[c+1][3]));
                float r1  = fmaxf(mx1 * s_cst[c + 1] + s_cst[16 + c + 1], 0.f);
                pk[c >> 1] = (unsigned int)f2bf(r0) | ((unsigned int)f2bf(r1) << 16);
            }
            int pos = (ph + 1) * 16 + (pw + 1);
            *(uint4*)&s_f1h[ig][pos * S1]     = make_uint4(pk[0], pk[1], pk[2], pk[3]);
            *(uint4*)&s_f1h[ig][pos * S1 + 8] = make_uint4(pk[4], pk[5], pk[6], pk[7]);
        }
    }
    __syncthreads();

    // ---------------- phase 2: conv2 via MFMA, pool -> s_f2h ----------------
    {
        const int m = wv4 & 1;                // M-tile (16 ch)
        const int x = lane & 15, half = lane >> 4;
        bf16x8 A2[5];
        #pragma unroll
        for (int s = 0; s < 5; s++)
            A2[s] = *(const bf16x8*)(const void*)(wsh + W2F_H + ((m * 5 + s) * 64 + lane) * 8);
        int voff[5];
        #pragma unroll
        for (int s = 0; s < 5; s++) {
            int tap = 2 * s + (half >> 1);
            int dy = (tap < 9) ? tap / 3 : 0, dx = (tap < 9) ? tap % 3 : 0;
            voff[s] = (dy * 16 + x + dx) * (2 * S1) + (half & 1) * 16;   // bytes
        }
        const int ch0 = m * 16 + half * 4;
        float a2v[4], c2v[4];
        #pragma unroll
        for (int r = 0; r < 4; r++) { a2v[r] = s_cst[32 + ch0 + r]; c2v[r] = s_cst[64 + ch0 + r]; }

        int p0 = (wv4 < 2) ? 0 : 4, p1 = (wv4 < 2) ? 4 : 7;
        for (int p = p0; p < p1; p++) {
            // 2 rows = 32 positions x (2*S1) bytes = 64*S1 bytes per p
            const char* base = (const char*)&s_f1h[img][0] + p * (64 * S1);
            f32x4 acc0 = {0.f, 0.f, 0.f, 0.f}, acc1 = {0.f, 0.f, 0.f, 0.f};
            #pragma unroll
            for (int s = 0; s < 5; s++) {
                bf16x8 b0 = *(const bf16x8*)(const void*)(base + voff[s]);
                bf16x8 b1 = *(const bf16x8*)(const void*)(base + 16 * 2 * S1 + voff[s]);
                acc0 = MFMA16(A2[s], b0, acc0);
                acc1 = MFMA16(A2[s], b1, acc1);
            }
            float hp[4];
            #pragma unroll
            for (int r = 0; r < 4; r++) {
                float vp = fmaxf(acc0[r], acc1[r]);
                hp[r] = fmaxf(vp, __shfl_xor(vp, 1));
            }
            if (!(x & 1) && x < 14) {
                int xp = x >> 1;
                unsigned int lo = (unsigned int)f2bf(fmaxf(hp[0] * a2v[0] + c2v[0], 0.f)) |
                                  ((unsigned int)f2bf(fmaxf(hp[1] * a2v[1] + c2v[1], 0.f)) << 16);
                unsigned int hi = (unsigned int)f2bf(fmaxf(hp[2] * a2v[2] + c2v[2], 0.f)) |
                                  ((unsigned int)f2bf(fmaxf(hp[3] * a2v[3] + c2v[3], 0.f)) << 16);
                *(uint2*)&s_f2h[img][((p + 1) * 9 + xp + 1) * S2 + ch0] = make_uint2(lo, hi);
            }
        }
    }
    __syncthreads();

    // ---------------- phase 3: conv3 via MFMA, pool -> s_flat ----------------
    {
        const int mt = wv4;                   // M-tile (16 of 64 ch)
        const int x8 = lane & 7, ry = (lane >> 3) & 1, half = lane >> 4;
        bf16x8 A3[9];
        #pragma unroll
        for (int ks = 0; ks < 9; ks++)
            A3[ks] = *(const bf16x8*)(const void*)(wsh + W3F_H + ((mt * 9 + ks) * 64 + lane) * 8);
        int voff3[9];
        #pragma unroll
        for (int ks = 0; ks < 9; ks++) {
            int dy = ks / 3, dx = ks % 3;
            voff3[ks] = ((ry + dy) * 9 + x8 + dx) * (2 * S2) + half * 16;  // bytes
        }
        const int ch0 = mt * 16 + half * 4;
        float a3v[4], c3v[4];
        #pragma unroll
        for (int r = 0; r < 4; r++) { a3v[r] = s_cst[96 + ch0 + r]; c3v[r] = s_cst[160 + ch0 + r]; }

        #pragma unroll
        for (int t = 0; t < 3; t++) {
            const char* base = (const char*)&s_f2h[img][0] + t * (2 * 9 * 2 * S2);  // 2 rows
            f32x4 acc = {0.f, 0.f, 0.f, 0.f};
            #pragma unroll
            for (int ks = 0; ks < 9; ks++) {
                bf16x8 bb = *(const bf16x8*)(const void*)(base + voff3[ks]);
                acc = MFMA16(A3[ks], bb, acc);
            }
            float hp[4];
            #pragma unroll
            for (int r = 0; r < 4; r++) {
                float vp = fmaxf(acc[r], __shfl_xor(acc[r], 8));
                hp[r] = fmaxf(vp, __shfl_xor(vp, 1));
            }
            if (ry == 0 && !(x8 & 1) && x8 < 6) {
                int xp = x8 >> 1;
                #pragma unroll
                for (int r = 0; r < 4; r++) {
                    float v = fmaxf(hp[r] * a3v[r] + c3v[r], 0.f);
                    s_flat[img][(ch0 + r) * 9 + t * 3 + xp] = f2bf(v);
                }
            }
        }
    }
    __syncthreads();

    // ---------------- phase 4: FC1 via MFMA, both images share weights -------
    {
        const int mt  = wv;                   // 0..7, 16 outputs each
        const int ib  = (lane >> 3) & 1;      // column 0-7 -> img0, 8-15 -> img1
        f32x4 acc = {0.f, 0.f, 0.f, 0.f};
        #pragma unroll
        for (int ks = 0; ks < 18; ks++) {
            bf16x8 a  = *(const bf16x8*)(const void*)(wsh + WFC1F_H + ((mt * 18 + ks) * 64 + lane) * 8);
            bf16x8 bb = *(const bf16x8*)(const void*)(&s_flat[ib][ks * 32 + (lane >> 4) * 8]);
            acc = MFMA16(a, bb, acc);
        }
        if ((lane & 7) == 0) {                // cols 0 and 8
            int ch0 = mt * 16 + (lane >> 4) * 4;
            #pragma unroll
            for (int r = 0; r < 4; r++)
                s_h[ib][ch0 + r] = fmaxf(acc[r] + bfc1[ch0 + r], 0.f);
        }
    }
    __syncthreads();

    // ---------------- phase 5: FC2 (both images) -----------------------------
    if (tid < 320) {
        int im = tid / 160, t = tid - im * 160;
        int o = t / 16, l = t & 15;
        float a = 0.f;
        #pragma unroll
        for (int k = l; k < 128; k += 16)
            a += s_h[im][k] * wfc2[o * 128 + k];
        a += __shfl_xor(a, 8);
        a += __shfl_xor(a, 4);
        a += __shfl_xor(a, 2);
        a += __shfl_xor(a, 1);
        if (l == 0) out[(b * 2 + im) * 10 + o] = a + bfc2[o];
    }
}

extern "C" void kernel_launch(void* const* d_in, const int* in_sizes, int n_in,
                              void* d_out, int out_size, void* d_ws, size_t ws_size,
                              hipStream_t stream) {
    float* ws = (float*)d_ws;
    prep_kernel<<<(PREP_ITEMS + 255) / 256, 256, 0, stream>>>(
        (const int*)d_in[1],                        // y_int
        (const float*)d_in[15],                     // w2
        (const float*)d_in[17],                     // w3
        (const float*)d_in[19],                     // w_fc1
        (const float*)d_in[2],                      // bias1
        (const float*)d_in[3], (const float*)d_in[4], (const float*)d_in[5], (const float*)d_in[6],
        (const float*)d_in[7], (const float*)d_in[8], (const float*)d_in[9], (const float*)d_in[10],
        (const float*)d_in[16],                     // bias2
        (const float*)d_in[11], (const float*)d_in[12], (const float*)d_in[13], (const float*)d_in[14],
        (const float*)d_in[18],                     // bias3
        ws);
    fused_cnn<<<512, 512, 0, stream>>>(
        (const int*)d_in[0],                        // x_img
        ws,
        (const float*)d_in[20],                     // b_fc1
        (const float*)d_in[21], (const float*)d_in[22],  // w_fc2, b_fc2
        (float*)d_out);
}